// Round 2
// baseline (475.120 us; speedup 1.0000x reference)
//
#include <hip/hip_runtime.h>
#include <math.h>

#define D 128
#define BLOCKS_A 768   // 3 blocks/CU resident with __launch_bounds__(256,3): whole grid co-resident
#define BLOCKS_C 1536  // 6 blocks/CU -> 24 waves/CU for the streaming phase
#define THREADS 256

typedef short s8v __attribute__((ext_vector_type(8)));
typedef float f4v __attribute__((ext_vector_type(4)));

__device__ __forceinline__ float fast_tanh(float z) {
    float e = __expf(2.f * z);
    return 1.f - 2.f / (e + 1.f);
}
// 1 VALU instr for 2 f32->bf16
__device__ __forceinline__ unsigned cvt_pk_bf16(float lo, float hi) {
    unsigned r;
    asm("v_cvt_pk_bf16_f32 %0, %1, %2" : "=v"(r) : "v"(lo), "v"(hi));
    return r;
}
__device__ __forceinline__ s8v pack8(float4 w0, float4 w1) {
    union { unsigned u[4]; s8v v; } r;
    r.u[0] = cvt_pk_bf16(w0.x, w0.y);
    r.u[1] = cvt_pk_bf16(w0.z, w0.w);
    r.u[2] = cvt_pk_bf16(w1.x, w1.y);
    r.u[3] = cvt_pk_bf16(w1.z, w1.w);
    return r.v;
}

// Phase A epilogue for one C-row-group RG_ (literal 0..3):
// x re-read from global in C-fragment layout (L1/L2-hot: this wave just
// streamed the tile), y = x*(1+tanh(z)), y -> x2s bf16 (coalesced uint4,
// same layout phase C reads), running per-lane segment sums.
#define EPI0(RG_)                                                             \
    {                                                                         \
        int r = R + quad * 4 + RG_;                                           \
        int seg = batch[r];                                                   \
        const float* xrow = x + (size_t)r * 128 + m15;                        \
        float yv[8];                                                          \
        _Pragma("unroll")                                                     \
        for (int t = 0; t < 8; ++t) {                                         \
            float z = af[t][RG_] + b2l[t];                                    \
            yv[t] = xrow[16 * t] * (1.f + fast_tanh(z));                      \
        }                                                                     \
        union { unsigned u[4]; uint4 q; } pk;                                 \
        pk.u[0] = cvt_pk_bf16(yv[0], yv[1]);                                  \
        pk.u[1] = cvt_pk_bf16(yv[2], yv[3]);                                  \
        pk.u[2] = cvt_pk_bf16(yv[4], yv[5]);                                  \
        pk.u[3] = cvt_pk_bf16(yv[6], yv[7]);                                  \
        ((uint4*)x2s)[(size_t)b * 256 + RG_ * 64 + lane] = pk.q;              \
        if (seg != cur) {                                                     \
            if (cur >= 0) {                                                   \
                _Pragma("unroll")                                             \
                for (int t = 0; t < 8; ++t)                                   \
                    atomicAdd(&sums[cur * 128 + m15 + 16 * t], acc[t]);       \
                if (m15 == 0) atomicAdd(&cnt[cur], acnt);                     \
            }                                                                 \
            cur = seg;                                                        \
            _Pragma("unroll")                                                 \
            for (int t = 0; t < 8; ++t) acc[t] = yv[t];                       \
            acnt = 1.f;                                                       \
        } else {                                                              \
            _Pragma("unroll")                                                 \
            for (int t = 0; t < 8; ++t) acc[t] += yv[t];                      \
            acnt += 1.f;                                                      \
        }                                                                     \
    }

// Phase A: x2 = x*(1+tanh(MLP(x))); segment sums + counts; x2 cached bf16.
// v2: weights live in LDS (shared across waves, written once), x A-fragments
// loaded straight from global in MFMA layout (no x LDS staging). VGPR ~130
// -> 3 waves/SIMD instead of 2.
__global__ __launch_bounds__(THREADS, 3) void phaseA(
    const float* __restrict__ x, const int* __restrict__ batch,
    const float* __restrict__ fc1_w, const float* __restrict__ fc1_b,
    const float* __restrict__ fc2_w, const float* __restrict__ fc2_b,
    float* __restrict__ sums, float* __restrict__ cnt,
    unsigned short* __restrict__ x2s, int N)
{
    __shared__ s8v wB1[2][4][64];       // GEMM1 B-fragments, 8 KB
    __shared__ s8v wB2[8][64];          // GEMM2 B-fragments, 8 KB
    __shared__ float hbuf[4][16 * 36];  // f32 hidden, pitch 36, wave-private

    const int lane = threadIdx.x & 63;
    const int wv = threadIdx.x >> 6;
    const int m15 = lane & 15;
    const int quad = lane >> 4;

    // --- wave 0 builds the weight fragments once; everyone else waits ---
    if (wv == 0) {
        #pragma unroll
        for (int t = 0; t < 2; ++t)
            #pragma unroll
            for (int kc = 0; kc < 4; ++kc) {
                const float* p = fc1_w + (16 * t + m15) * 128 + kc * 32 + quad * 8;
                wB1[t][kc][lane] = pack8(*(const float4*)p, *(const float4*)(p + 4));
            }
        #pragma unroll
        for (int t = 0; t < 8; ++t) {
            const float* p = fc2_w + (16 * t + m15) * 32 + quad * 8;
            wB2[t][lane] = pack8(*(const float4*)p, *(const float4*)(p + 4));
        }
    }
    float b1l[2], b2l[8];
    #pragma unroll
    for (int t = 0; t < 2; ++t) b1l[t] = fc1_b[m15 + 16 * t];
    #pragma unroll
    for (int t = 0; t < 8; ++t) b2l[t] = fc2_b[m15 + 16 * t];
    __syncthreads();

    // --- balanced contiguous 16-row blocks per wave ---
    const int total16 = N >> 4;
    const int nw = BLOCKS_A * 4;
    const int gw = blockIdx.x * 4 + wv;
    const int base = total16 / nw, rem = total16 % nw;
    const int b0 = gw * base + (gw < rem ? gw : rem);
    const int b1e = b0 + base + (gw < rem ? 1 : 0);

    float* hw = hbuf[wv];

    float acc[8];
    #pragma unroll
    for (int t = 0; t < 8; ++t) acc[t] = 0.f;
    int cur = -1;
    float acnt = 0.f;
    const f4v z4 = {0.f, 0.f, 0.f, 0.f};

    // software pipeline: F holds the in-flight x tile, already in MFMA
    // A-fragment layout: row m15, cols kc*32 + quad*8 (+4 for the 2nd half)
    float4 F[8];
    if (b0 < b1e) {
        const float* xp = x + (size_t)(b0 << 4) * D + m15 * 128 + quad * 8;
        #pragma unroll
        for (int kc = 0; kc < 4; ++kc) {
            F[2 * kc]     = *(const float4*)(xp + kc * 32);
            F[2 * kc + 1] = *(const float4*)(xp + kc * 32 + 4);
        }
    }

    for (int b = b0; b < b1e; ++b) {
        const int R = b << 4;
        // convert arrived fragments, then issue next-tile loads
        s8v ax[4];
        #pragma unroll
        for (int kc = 0; kc < 4; ++kc)
            ax[kc] = pack8(F[2 * kc], F[2 * kc + 1]);
        if (b + 1 < b1e) {
            const float* xp = x + (size_t)((b + 1) << 4) * D + m15 * 128 + quad * 8;
            #pragma unroll
            for (int kc = 0; kc < 4; ++kc) {
                F[2 * kc]     = *(const float4*)(xp + kc * 32);
                F[2 * kc + 1] = *(const float4*)(xp + kc * 32 + 4);
            }
        }
        // GEMM1: h[16][32] = x @ W1^T  (B-fragments streamed from LDS)
        f4v accH[2];
        accH[0] = z4; accH[1] = z4;
        #pragma unroll
        for (int kc = 0; kc < 4; ++kc) {
            accH[0] = __builtin_amdgcn_mfma_f32_16x16x32_bf16(ax[kc], wB1[0][kc][lane], accH[0], 0, 0, 0);
            accH[1] = __builtin_amdgcn_mfma_f32_16x16x32_bf16(ax[kc], wB1[1][kc][lane], accH[1], 0, 0, 0);
        }
        // bias + ReLU -> LDS (layout change for GEMM2 A-fragment)
        #pragma unroll
        for (int t = 0; t < 2; ++t)
            #pragma unroll
            for (int rg = 0; rg < 4; ++rg) {
                float hv = fmaxf(accH[t][rg] + b1l[t], 0.f);
                hw[(quad * 4 + rg) * 36 + m15 + 16 * t] = hv;
            }
        const f4v h0 = *(const f4v*)&hw[m15 * 36 + quad * 8];
        const f4v h1 = *(const f4v*)&hw[m15 * 36 + quad * 8 + 4];
        union { unsigned u[4]; s8v v; } ahu;
        ahu.u[0] = cvt_pk_bf16(h0[0], h0[1]);
        ahu.u[1] = cvt_pk_bf16(h0[2], h0[3]);
        ahu.u[2] = cvt_pk_bf16(h1[0], h1[1]);
        ahu.u[3] = cvt_pk_bf16(h1[2], h1[3]);
        s8v ah = ahu.v;
        // GEMM2: a[16][128] = h @ W2^T
        f4v af[8];
        #pragma unroll
        for (int t = 0; t < 8; ++t)
            af[t] = __builtin_amdgcn_mfma_f32_16x16x32_bf16(ah, wB2[t][lane], z4, 0, 0, 0);

        EPI0(0) EPI0(1) EPI0(2) EPI0(3)
    }
    if (cur >= 0) {
        #pragma unroll
        for (int t = 0; t < 8; ++t)
            atomicAdd(&sums[cur * 128 + m15 + 16 * t], acc[t]);
        if (m15 == 0) atomicAdd(&cnt[cur], acnt);
    }
}

// tg = tanh((sums/max(cnt,1)) @ Wm), one 128-thread block per segment
__global__ __launch_bounds__(D, 8) void phaseB(
    const float* __restrict__ sums, const float* __restrict__ cnt,
    const float* __restrict__ Wm, float* __restrict__ tg)
{
    int b = blockIdx.x;
    int d = threadIdx.x;
    __shared__ float m[D];
    float inv = 1.f / fmaxf(cnt[b], 1.f);
    m[d] = sums[(b << 7) + d] * inv;
    __syncthreads();
    float acc = 0.f;
    #pragma unroll 8
    for (int k = 0; k < D; ++k)
        acc = fmaf(m[k], Wm[(k << 7) + d], acc);
    tg[(b << 7) + d] = fast_tanh(acc);
}

// Phase C: stream cached x2 (bf16), coef = sigmoid(<x2, tg[seg]>),
// out += coef*x2. Pure streaming: no LDS/MFMA/SW-pipeline; rely on 24
// waves/CU TLP for latency hiding. BW floor ~145 MB.
__global__ __launch_bounds__(THREADS, 6) void phaseC(
    const unsigned short* __restrict__ x2s, const int* __restrict__ batch,
    const float* __restrict__ tg, float* __restrict__ out, int N)
{
    const int lane = threadIdx.x & 63;
    const int wv = threadIdx.x >> 6;
    const int m15 = lane & 15;
    const int quad = lane >> 4;

    const int total16 = N >> 4;
    const int nw = BLOCKS_C * 4;
    const int gw = blockIdx.x * 4 + wv;
    const int base = total16 / nw, rem = total16 % nw;
    const int b0 = gw * base + (gw < rem ? gw : rem);
    const int b1e = b0 + base + (gw < rem ? 1 : 0);

    float acc[8], tgv[8];
    #pragma unroll
    for (int t = 0; t < 8; ++t) { acc[t] = 0.f; tgv[t] = 0.f; }
    int cur = -1;

    for (int b = b0; b < b1e; ++b) {
        const int R = b << 4;
        const uint4* p = (const uint4*)x2s + (size_t)b * 256 + lane;
        uint4 C0 = p[0], C1 = p[64], C2 = p[128], C3 = p[192];
        int sg0 = batch[R + quad * 4 + 0];
        int sg1 = batch[R + quad * 4 + 1];
        int sg2 = batch[R + quad * 4 + 2];
        int sg3 = batch[R + quad * 4 + 3];
        #pragma unroll
        for (int rg = 0; rg < 4; ++rg) {
            uint4 C = rg == 0 ? C0 : rg == 1 ? C1 : rg == 2 ? C2 : C3;
            int seg = rg == 0 ? sg0 : rg == 1 ? sg1 : rg == 2 ? sg2 : sg3;
            if (seg != cur) {
                if (cur >= 0) {
                    #pragma unroll
                    for (int t = 0; t < 8; ++t)
                        atomicAdd(&out[cur * 128 + m15 + 16 * t], acc[t]);
                }
                cur = seg;
                #pragma unroll
                for (int t = 0; t < 8; ++t) {
                    tgv[t] = tg[seg * 128 + m15 + 16 * t];
                    acc[t] = 0.f;
                }
            }
            float xv[8];
            unsigned w;
            union { unsigned u; float f; } cv;
            w = C.x; cv.u = w << 16; xv[0] = cv.f; cv.u = w & 0xffff0000u; xv[1] = cv.f;
            w = C.y; cv.u = w << 16; xv[2] = cv.f; cv.u = w & 0xffff0000u; xv[3] = cv.f;
            w = C.z; cv.u = w << 16; xv[4] = cv.f; cv.u = w & 0xffff0000u; xv[5] = cv.f;
            w = C.w; cv.u = w << 16; xv[6] = cv.f; cv.u = w & 0xffff0000u; xv[7] = cv.f;
            float dot = 0.f;
            #pragma unroll
            for (int t = 0; t < 8; ++t) dot = fmaf(xv[t], tgv[t], dot);
            dot += __shfl_xor(dot, 1);
            dot += __shfl_xor(dot, 2);
            dot += __shfl_xor(dot, 4);
            dot += __shfl_xor(dot, 8);
            float coef = 1.f / (1.f + __expf(-dot));
            #pragma unroll
            for (int t = 0; t < 8; ++t) acc[t] = fmaf(coef, xv[t], acc[t]);
        }
    }
    if (cur >= 0) {
        #pragma unroll
        for (int t = 0; t < 8; ++t)
            atomicAdd(&out[cur * 128 + m15 + 16 * t], acc[t]);
    }
}

extern "C" void kernel_launch(void* const* d_in, const int* in_sizes, int n_in,
                              void* d_out, int out_size, void* d_ws, size_t ws_size,
                              hipStream_t stream) {
    const float* x     = (const float*)d_in[0];
    const int*   batch = (const int*)d_in[1];
    const float* Wm    = (const float*)d_in[3];
    const float* fc1_w = (const float*)d_in[4];
    const float* fc1_b = (const float*)d_in[5];
    const float* fc2_w = (const float*)d_in[6];
    const float* fc2_b = (const float*)d_in[7];
    float* out = (float*)d_out;

    int N = in_sizes[0] / D;
    int B = out_size / D;

    float* sums = (float*)d_ws;                        // [B,128]
    float* cnt  = sums + (size_t)B * D;                // [B]
    float* tg   = cnt + B;                             // [B,128]
    unsigned short* x2s = (unsigned short*)(tg + (size_t)B * D); // [N,128] bf16

    hipMemsetAsync(d_ws, 0, ((size_t)B * D + B) * sizeof(float), stream);
    hipMemsetAsync(d_out, 0, (size_t)out_size * sizeof(float), stream);

    phaseA<<<BLOCKS_A, THREADS, 0, stream>>>(
        x, batch, fc1_w, fc1_b, fc2_w, fc2_b, sums, cnt, x2s, N);
    phaseB<<<B, D, 0, stream>>>(sums, cnt, Wm, tg);
    phaseC<<<BLOCKS_C, THREADS, 0, stream>>>(x2s, batch, tg, out, N);
}

// Round 3
// 447.655 us; speedup vs baseline: 1.0614x; 1.0614x over previous
//
#include <hip/hip_runtime.h>
#include <math.h>

#define D 128
#define BLOCKS_A 768   // 3 blocks/CU resident with __launch_bounds__(256,3)
#define BLOCKS_C 1536
#define THREADS 256

typedef short s8v __attribute__((ext_vector_type(8)));
typedef float f4v __attribute__((ext_vector_type(4)));

__device__ __forceinline__ float fast_tanh(float z) {
    float e = __expf(2.f * z);
    return 1.f - 2.f / (e + 1.f);
}
__device__ __forceinline__ unsigned cvt_pk_bf16(float lo, float hi) {
    unsigned r;
    asm("v_cvt_pk_bf16_f32 %0, %1, %2" : "=v"(r) : "v"(lo), "v"(hi));
    return r;
}
__device__ __forceinline__ s8v pack8(float4 w0, float4 w1) {
    union { unsigned u[4]; s8v v; } r;
    r.u[0] = cvt_pk_bf16(w0.x, w0.y);
    r.u[1] = cvt_pk_bf16(w0.z, w0.w);
    r.u[2] = cvt_pk_bf16(w1.x, w1.y);
    r.u[3] = cvt_pk_bf16(w1.z, w1.w);
    return r.v;
}

// Cross-quad reduce (quads hold the same columns m15+16t for different row
// subsets) then ONE atomic per address: lane flushes only its 2 owned t's.
// Replaces the old 512-ops-to-128-addresses flush (4-way same-address
// serialization in-wave) with 128 ops, 1-way.
#define RFLUSH(ACC_, SEG_, DST_)                                              \
    if ((SEG_) >= 0) {                                                        \
        _Pragma("unroll")                                                     \
        for (int t = 0; t < 8; ++t) {                                         \
            ACC_[t] += __shfl_xor(ACC_[t], 16);                               \
            ACC_[t] += __shfl_xor(ACC_[t], 32);                               \
        }                                                                     \
        _Pragma("unroll")                                                     \
        for (int t = 0; t < 8; ++t)                                           \
            if ((t >> 1) == quad)                                             \
                atomicAdd(&(DST_)[(size_t)(SEG_) * 128 + m15 + 16 * t], ACC_[t]); \
    }

// Phase A epilogue for one C-row-group RG_ (literal 0..3): y = x*(1+tanh(z)),
// y -> x2s bf16 (coalesced, same layout phase C reads), y bucketed into
// tl (seg==segLo) / th (seg==segHi) / direct-atomic (ultra-rare 3rd segment).
#define EPI0(RG_)                                                             \
    {                                                                         \
        int r = R + quad * 4 + RG_;                                           \
        int seg = batch[r];                                                   \
        const float* xrow = x + (size_t)r * 128 + m15;                        \
        float yv[8];                                                          \
        _Pragma("unroll")                                                     \
        for (int t = 0; t < 8; ++t) {                                         \
            float z = af[t][RG_] + b2l[t];                                    \
            yv[t] = xrow[16 * t] * (1.f + fast_tanh(z));                      \
        }                                                                     \
        union { unsigned u[4]; uint4 q; } pk;                                 \
        pk.u[0] = cvt_pk_bf16(yv[0], yv[1]);                                  \
        pk.u[1] = cvt_pk_bf16(yv[2], yv[3]);                                  \
        pk.u[2] = cvt_pk_bf16(yv[4], yv[5]);                                  \
        pk.u[3] = cvt_pk_bf16(yv[6], yv[7]);                                  \
        ((uint4*)x2s)[(size_t)b * 256 + RG_ * 64 + lane] = pk.q;              \
        if (seg == segLo) {                                                   \
            _Pragma("unroll")                                                 \
            for (int t = 0; t < 8; ++t) tl[t] += yv[t];                       \
        } else if (seg == segHi) {                                            \
            _Pragma("unroll")                                                 \
            for (int t = 0; t < 8; ++t) th[t] += yv[t];                       \
        } else {                                                              \
            _Pragma("unroll")                                                 \
            for (int t = 0; t < 8; ++t)                                       \
                atomicAdd(&sums[(size_t)seg * 128 + m15 + 16 * t], yv[t]);    \
        }                                                                     \
    }

// Phase A: x2 = x*(1+tanh(MLP(x))); wave-level segment sums; x2 cached bf16.
__global__ __launch_bounds__(THREADS, 3) void phaseA(
    const float* __restrict__ x, const int* __restrict__ batch,
    const float* __restrict__ fc1_w, const float* __restrict__ fc1_b,
    const float* __restrict__ fc2_w, const float* __restrict__ fc2_b,
    float* __restrict__ sums, unsigned short* __restrict__ x2s, int N)
{
    __shared__ s8v wB1[2][4][64];       // GEMM1 B-fragments, 8 KB
    __shared__ s8v wB2[8][64];          // GEMM2 B-fragments, 8 KB
    __shared__ float hbuf[4][16 * 36];  // f32 hidden, pitch 36, wave-private

    const int lane = threadIdx.x & 63;
    const int wv = threadIdx.x >> 6;
    const int m15 = lane & 15;
    const int quad = lane >> 4;

    if (wv == 0) {
        #pragma unroll
        for (int t = 0; t < 2; ++t)
            #pragma unroll
            for (int kc = 0; kc < 4; ++kc) {
                const float* p = fc1_w + (16 * t + m15) * 128 + kc * 32 + quad * 8;
                wB1[t][kc][lane] = pack8(*(const float4*)p, *(const float4*)(p + 4));
            }
        #pragma unroll
        for (int t = 0; t < 8; ++t) {
            const float* p = fc2_w + (16 * t + m15) * 32 + quad * 8;
            wB2[t][lane] = pack8(*(const float4*)p, *(const float4*)(p + 4));
        }
    }
    float b1l[2], b2l[8];
    #pragma unroll
    for (int t = 0; t < 2; ++t) b1l[t] = fc1_b[m15 + 16 * t];
    #pragma unroll
    for (int t = 0; t < 8; ++t) b2l[t] = fc2_b[m15 + 16 * t];
    __syncthreads();

    const int total16 = N >> 4;
    const int nw = BLOCKS_A * 4;
    const int gw = blockIdx.x * 4 + wv;
    const int base = total16 / nw, rem = total16 % nw;
    const int b0 = gw * base + (gw < rem ? gw : rem);
    const int b1e = b0 + base + (gw < rem ? 1 : 0);

    float* hw = hbuf[wv];

    float accW[8];
    #pragma unroll
    for (int t = 0; t < 8; ++t) accW[t] = 0.f;
    int curW = -1;
    const f4v z4 = {0.f, 0.f, 0.f, 0.f};

    // software pipeline: F holds the in-flight x tile in MFMA A-layout
    float4 F[8];
    if (b0 < b1e) {
        const float* xp = x + (size_t)(b0 << 4) * D + m15 * 128 + quad * 8;
        #pragma unroll
        for (int kc = 0; kc < 4; ++kc) {
            F[2 * kc]     = *(const float4*)(xp + kc * 32);
            F[2 * kc + 1] = *(const float4*)(xp + kc * 32 + 4);
        }
    }

    for (int b = b0; b < b1e; ++b) {
        const int R = b << 4;
        s8v ax[4];
        #pragma unroll
        for (int kc = 0; kc < 4; ++kc)
            ax[kc] = pack8(F[2 * kc], F[2 * kc + 1]);
        if (b + 1 < b1e) {
            const float* xp = x + (size_t)((b + 1) << 4) * D + m15 * 128 + quad * 8;
            #pragma unroll
            for (int kc = 0; kc < 4; ++kc) {
                F[2 * kc]     = *(const float4*)(xp + kc * 32);
                F[2 * kc + 1] = *(const float4*)(xp + kc * 32 + 4);
            }
        }
        // GEMM1: h[16][32] = x @ W1^T
        f4v accH[2];
        accH[0] = z4; accH[1] = z4;
        #pragma unroll
        for (int kc = 0; kc < 4; ++kc) {
            accH[0] = __builtin_amdgcn_mfma_f32_16x16x32_bf16(ax[kc], wB1[0][kc][lane], accH[0], 0, 0, 0);
            accH[1] = __builtin_amdgcn_mfma_f32_16x16x32_bf16(ax[kc], wB1[1][kc][lane], accH[1], 0, 0, 0);
        }
        #pragma unroll
        for (int t = 0; t < 2; ++t)
            #pragma unroll
            for (int rg = 0; rg < 4; ++rg) {
                float hv = fmaxf(accH[t][rg] + b1l[t], 0.f);
                hw[(quad * 4 + rg) * 36 + m15 + 16 * t] = hv;
            }
        const f4v h0 = *(const f4v*)&hw[m15 * 36 + quad * 8];
        const f4v h1 = *(const f4v*)&hw[m15 * 36 + quad * 8 + 4];
        union { unsigned u[4]; s8v v; } ahu;
        ahu.u[0] = cvt_pk_bf16(h0[0], h0[1]);
        ahu.u[1] = cvt_pk_bf16(h0[2], h0[3]);
        ahu.u[2] = cvt_pk_bf16(h1[0], h1[1]);
        ahu.u[3] = cvt_pk_bf16(h1[2], h1[3]);
        s8v ah = ahu.v;
        // GEMM2: a[16][128] = h @ W2^T
        f4v af[8];
        #pragma unroll
        for (int t = 0; t < 8; ++t)
            af[t] = __builtin_amdgcn_mfma_f32_16x16x32_bf16(ah, wB2[t][lane], z4, 0, 0, 0);

        // ---- epilogue with wave-level segment buckets ----
        const int segLo = batch[R];       // sorted batch: tile spans <=2 segs
        const int segHi = batch[R + 15];  // (3rd-segment fallback kept for safety)
        float tl[8], th[8];
        #pragma unroll
        for (int t = 0; t < 8; ++t) { tl[t] = 0.f; th[t] = 0.f; }

        EPI0(0) EPI0(1) EPI0(2) EPI0(3)

        if (segLo == curW) {
            #pragma unroll
            for (int t = 0; t < 8; ++t) accW[t] += tl[t];
        } else {
            RFLUSH(accW, curW, sums)
            curW = segLo;
            #pragma unroll
            for (int t = 0; t < 8; ++t) accW[t] = tl[t];
        }
        if (segHi != segLo) {
            RFLUSH(accW, curW, sums)
            curW = segHi;
            #pragma unroll
            for (int t = 0; t < 8; ++t) accW[t] = th[t];
        }
    }
    RFLUSH(accW, curW, sums)
}

// tg = tanh((sums/count) @ Wm); counts from binary search on sorted batch
// (no cnt atomics anywhere). One 128-thread block per segment.
__global__ __launch_bounds__(D, 8) void phaseB(
    const float* __restrict__ sums, const int* __restrict__ batch,
    const float* __restrict__ Wm, float* __restrict__ tg, int N)
{
    int b = blockIdx.x;
    int d = threadIdx.x;
    __shared__ float m[D];
    __shared__ int bnd[2];
    if (d < 2) {
        int target = b + d;  // lower_bound(batch, b) and lower_bound(batch, b+1)
        int lo = 0, hi = N;
        while (lo < hi) {
            int mid = (lo + hi) >> 1;
            if (batch[mid] < target) lo = mid + 1; else hi = mid;
        }
        bnd[d] = lo;
    }
    __syncthreads();
    float inv = 1.f / fmaxf((float)(bnd[1] - bnd[0]), 1.f);
    m[d] = sums[(b << 7) + d] * inv;
    __syncthreads();
    float acc = 0.f;
    #pragma unroll 8
    for (int k = 0; k < D; ++k)
        acc = fmaf(m[k], Wm[(k << 7) + d], acc);
    tg[(b << 7) + d] = fast_tanh(acc);
}

__device__ __forceinline__ float bf_lo(unsigned w) {
    union { unsigned u; float f; } v; v.u = w << 16; return v.f;
}
__device__ __forceinline__ float bf_hi(unsigned w) {
    union { unsigned u; float f; } v; v.u = w & 0xffff0000u; return v.f;
}

// Phase C: stream cached x2 (bf16), coef = sigmoid(<x2, tg[seg]>),
// out += coef*x2 with the same wave-level bucket flush as phase A.
__global__ __launch_bounds__(THREADS, 4) void phaseC(
    const unsigned short* __restrict__ x2s, const int* __restrict__ batch,
    const float* __restrict__ tg, float* __restrict__ out, int N)
{
    const int lane = threadIdx.x & 63;
    const int wv = threadIdx.x >> 6;
    const int m15 = lane & 15;
    const int quad = lane >> 4;

    const int total16 = N >> 4;
    const int nw = BLOCKS_C * 4;
    const int gw = blockIdx.x * 4 + wv;
    const int base = total16 / nw, rem = total16 % nw;
    const int b0 = gw * base + (gw < rem ? gw : rem);
    const int b1e = b0 + base + (gw < rem ? 1 : 0);

    float accW[8], tgv[8];
    #pragma unroll
    for (int t = 0; t < 8; ++t) { accW[t] = 0.f; tgv[t] = 0.f; }
    int curW = -1;
    int curT = -1;  // per-lane tg cache tracker (quad-group uniform)

    for (int b = b0; b < b1e; ++b) {
        const int R = b << 4;
        const uint4* p = (const uint4*)x2s + (size_t)b * 256 + lane;
        uint4 C0 = p[0], C1 = p[64], C2 = p[128], C3 = p[192];
        const int segLo = batch[R];
        const int segHi = batch[R + 15];
        float tl[8], th[8];
        #pragma unroll
        for (int t = 0; t < 8; ++t) { tl[t] = 0.f; th[t] = 0.f; }

        #pragma unroll
        for (int rg = 0; rg < 4; ++rg) {
            uint4 C = rg == 0 ? C0 : rg == 1 ? C1 : rg == 2 ? C2 : C3;
            int seg = batch[R + quad * 4 + rg];
            if (seg != curT) {
                curT = seg;
                #pragma unroll
                for (int t = 0; t < 8; ++t)
                    tgv[t] = tg[(size_t)seg * 128 + m15 + 16 * t];
            }
            float xv[8];
            xv[0] = bf_lo(C.x); xv[1] = bf_hi(C.x);
            xv[2] = bf_lo(C.y); xv[3] = bf_hi(C.y);
            xv[4] = bf_lo(C.z); xv[5] = bf_hi(C.z);
            xv[6] = bf_lo(C.w); xv[7] = bf_hi(C.w);
            float dot = 0.f;
            #pragma unroll
            for (int t = 0; t < 8; ++t) dot = fmaf(xv[t], tgv[t], dot);
            dot += __shfl_xor(dot, 1);
            dot += __shfl_xor(dot, 2);
            dot += __shfl_xor(dot, 4);
            dot += __shfl_xor(dot, 8);
            float coef = 1.f / (1.f + __expf(-dot));
            if (seg == segLo) {
                #pragma unroll
                for (int t = 0; t < 8; ++t) tl[t] = fmaf(coef, xv[t], tl[t]);
            } else if (seg == segHi) {
                #pragma unroll
                for (int t = 0; t < 8; ++t) th[t] = fmaf(coef, xv[t], th[t]);
            } else {
                #pragma unroll
                for (int t = 0; t < 8; ++t)
                    atomicAdd(&out[(size_t)seg * 128 + m15 + 16 * t], coef * xv[t]);
            }
        }

        if (segLo == curW) {
            #pragma unroll
            for (int t = 0; t < 8; ++t) accW[t] += tl[t];
        } else {
            RFLUSH(accW, curW, out)
            curW = segLo;
            #pragma unroll
            for (int t = 0; t < 8; ++t) accW[t] = tl[t];
        }
        if (segHi != segLo) {
            RFLUSH(accW, curW, out)
            curW = segHi;
            #pragma unroll
            for (int t = 0; t < 8; ++t) accW[t] = th[t];
        }
    }
    RFLUSH(accW, curW, out)
}

extern "C" void kernel_launch(void* const* d_in, const int* in_sizes, int n_in,
                              void* d_out, int out_size, void* d_ws, size_t ws_size,
                              hipStream_t stream) {
    const float* x     = (const float*)d_in[0];
    const int*   batch = (const int*)d_in[1];
    const float* Wm    = (const float*)d_in[3];
    const float* fc1_w = (const float*)d_in[4];
    const float* fc1_b = (const float*)d_in[5];
    const float* fc2_w = (const float*)d_in[6];
    const float* fc2_b = (const float*)d_in[7];
    float* out = (float*)d_out;

    int N = in_sizes[0] / D;
    int B = out_size / D;

    float* sums = (float*)d_ws;                        // [B,128]
    float* tg   = sums + (size_t)B * D;                // [B,128]
    unsigned short* x2s = (unsigned short*)(tg + (size_t)B * D); // [N,128] bf16

    hipMemsetAsync(d_ws, 0, (size_t)B * D * sizeof(float), stream);
    hipMemsetAsync(d_out, 0, (size_t)out_size * sizeof(float), stream);

    phaseA<<<BLOCKS_A, THREADS, 0, stream>>>(
        x, batch, fc1_w, fc1_b, fc2_w, fc2_b, sums, x2s, N);
    phaseB<<<B, D, 0, stream>>>(sums, batch, Wm, tg, N);
    phaseC<<<BLOCKS_C, THREADS, 0, stream>>>(x2s, batch, tg, out, N);
}